// Round 4
// baseline (79462.653 us; speedup 1.0000x reference)
//
#include <hip/hip_runtime.h>
#include <math.h>

#define F_DIM 128
#define EMB 300
#define HID 512
#define NSTEP 4096
#define NNBR 64
#define GWGS 32    // workgroups per recurrent group (F and L)
#define NWG 512    // launched WGs; 64 winners elected on one XCD
#define LSTR 36    // LDS row stride (floats)

typedef unsigned long long ull;

__device__ __forceinline__ float sigmf(float x){ return 1.0f/(1.0f + __expf(-x)); }
__device__ __forceinline__ float tanhfast(float x){
  float t = __expf(2.0f*x);
  return (t - 1.0f)/(t + 1.0f);
}

__device__ __forceinline__ float red16(float v){
  v += __shfl_xor(v, 8);
  v += __shfl_xor(v, 4);
  v += __shfl_xor(v, 2);
  v += __shfl_xor(v, 1);
  return v;
}

// ---- sc0 (L1-bypass, L2-service) memory ops: coherent across WGs on one XCD ----
__device__ __forceinline__ void l2load2(const ull* p, ull& a, ull& b){
  asm volatile("global_load_dwordx2 %0, %2, off sc0\n\t"
               "global_load_dwordx2 %1, %2, off offset:8 sc0\n\t"
               "s_waitcnt vmcnt(0)"
               : "=&v"(a), "=&v"(b) : "v"(p) : "memory");
}
__device__ __forceinline__ void l2load4(const ull* ps, const ull* pf,
                                        ull& s0, ull& s1, ull& f0, ull& f1){
  asm volatile("global_load_dwordx2 %0, %4, off sc0\n\t"
               "global_load_dwordx2 %1, %4, off offset:8 sc0\n\t"
               "global_load_dwordx2 %2, %5, off sc0\n\t"
               "global_load_dwordx2 %3, %5, off offset:8 sc0\n\t"
               "s_waitcnt vmcnt(0)"
               : "=&v"(s0), "=&v"(s1), "=&v"(f0), "=&v"(f1)
               : "v"(ps), "v"(pf) : "memory");
}
__device__ __forceinline__ void l2store(ull* p, ull v){
  asm volatile("global_store_dwordx2 %0, %1, off sc0" : : "v"(p), "v"(v) : "memory");
}

__device__ __forceinline__ bool badtag(ull a, ull b, unsigned tag){
  return ((((unsigned)(a>>32)) ^ tag) | (((unsigned)(b>>32)) ^ tag)) != 0u;
}

// poll fast (L2/sc0) path; every 64th iter fall back to agent-scope mirror
__device__ __forceinline__ void pollpair(const ull* p, const ull* pm, unsigned tag,
                                         ull& a, ull& b){
  unsigned it = 0;
  while (badtag(a, b, tag)){
    if ((++it & 63u) == 0u){
      a = __hip_atomic_load((ull*)pm,   __ATOMIC_RELAXED, __HIP_MEMORY_SCOPE_AGENT);
      b = __hip_atomic_load((ull*)pm+1, __ATOMIC_RELAXED, __HIP_MEMORY_SCOPE_AGENT);
    } else {
      l2load2(p, a, b);
    }
  }
}

// ---------------- generic tiled f32 GEMM: C[M,N] = A[M,K]@B[K,N] (+D) (+bias_n) ----
__global__ void gemm_tiled(const float* __restrict__ A, int lda,
                           const float* __restrict__ B, int ldb, int transB,
                           const float* __restrict__ D, int ldd,
                           const float* __restrict__ bias,
                           float* __restrict__ C, int ldc,
                           int M, int N, int K)
{
  __shared__ float As[16][65];
  __shared__ float Bs[16][65];
  const int tid = threadIdx.x;
  const int m0 = blockIdx.y*64, n0 = blockIdx.x*64;
  const int ty = tid>>4, tx = tid&15;
  float acc[4][4] = {};
  for (int k0=0; k0<K; k0+=16){
    #pragma unroll
    for (int i=0;i<4;i++){
      int idx = tid + i*256;
      int m = idx>>4, k = idx&15;
      float va = 0.f;
      if (m0+m < M && k0+k < K) va = A[(size_t)(m0+m)*lda + k0+k];
      As[k][m] = va;
      int k2 = idx>>6, n = idx&63;
      float vb = 0.f;
      if (k0+k2 < K && n0+n < N)
        vb = transB ? B[(size_t)(n0+n)*ldb + k0+k2] : B[(size_t)(k0+k2)*ldb + n0+n];
      Bs[k2][n] = vb;
    }
    __syncthreads();
    #pragma unroll
    for (int k=0;k<16;k++){
      float a[4], b[4];
      #pragma unroll
      for (int i=0;i<4;i++) a[i] = As[k][ty*4+i];
      #pragma unroll
      for (int j=0;j<4;j++) b[j] = Bs[k][tx*4+j];
      #pragma unroll
      for (int i=0;i<4;i++)
        #pragma unroll
        for (int j=0;j<4;j++) acc[i][j] += a[i]*b[j];
    }
    __syncthreads();
  }
  #pragma unroll
  for (int i=0;i<4;i++){
    int m = m0 + ty*4 + i;
    if (m >= M) continue;
    #pragma unroll
    for (int j=0;j<4;j++){
      int n = n0 + tx*4 + j;
      if (n >= N) continue;
      float v = acc[i][j];
      if (D)    v += D[(size_t)m*ldd + n];
      if (bias) v += bias[n];
      C[(size_t)m*ldc + n] = v;
    }
  }
}

// ---------------- matvec: out[m] = sum_k A[m,k]*x[k] (+bias[m]); transA reads A[k,m]
__global__ void matvec(const float* __restrict__ A, int lda, int transA,
                       const float* __restrict__ x, const float* __restrict__ bias,
                       float* __restrict__ out, int M, int K)
{
  const int wave = threadIdx.x>>6, lane = threadIdx.x&63;
  const int row = blockIdx.x*4 + wave;
  if (row >= M) return;
  float s = 0.f;
  for (int k=lane; k<K; k+=64)
    s += (transA ? A[(size_t)k*lda + row] : A[(size_t)row*lda + k]) * x[k];
  s += __shfl_xor(s,32); s += __shfl_xor(s,16); s += __shfl_xor(s,8);
  s += __shfl_xor(s,4);  s += __shfl_xor(s,2);  s += __shfl_xor(s,1);
  if (lane==0) out[row] = s + (bias ? bias[row] : 0.f);
}

// ---------------- attention precompute: aggr[t] = softmax((v_t+e_t)@u) @ (v_t+e_t)
__global__ void attn_kernel(const float* __restrict__ V, const float* __restrict__ E,
                            const float* __restrict__ u, float* __restrict__ aggr)
{
  __shared__ float Es[NNBR][F_DIM+1];
  __shared__ float us[F_DIM];
  __shared__ float attn[NNBR];
  const int t = blockIdx.x, tid = threadIdx.x;
  if (tid < F_DIM) us[tid] = u[tid];
  const float* e = E + (size_t)t*NNBR*F_DIM;
  const float* v = V + (size_t)t*F_DIM;
  for (int idx=tid; idx<NNBR*F_DIM; idx+=256){
    int k = idx>>7, f = idx&127;
    Es[k][f] = e[idx] + v[f];
  }
  __syncthreads();
  if (tid < NNBR){
    float s = 0.f;
    #pragma unroll
    for (int f=0; f<F_DIM; f++) s += Es[tid][f]*us[f];
    float m = s;
    m = fmaxf(m, __shfl_xor(m,32)); m = fmaxf(m, __shfl_xor(m,16));
    m = fmaxf(m, __shfl_xor(m,8));  m = fmaxf(m, __shfl_xor(m,4));
    m = fmaxf(m, __shfl_xor(m,2));  m = fmaxf(m, __shfl_xor(m,1));
    float p = expf(s - m);
    float sum = p;
    sum += __shfl_xor(sum,32); sum += __shfl_xor(sum,16); sum += __shfl_xor(sum,8);
    sum += __shfl_xor(sum,4);  sum += __shfl_xor(sum,2);  sum += __shfl_xor(sum,1);
    attn[tid] = p / sum;
  }
  __syncthreads();
  if (tid < F_DIM){
    float a = 0.f;
    #pragma unroll
    for (int k=0; k<NNBR; k++) a += attn[k]*Es[k][tid];
    aggr[(size_t)t*F_DIM + tid] = a;
  }
}

// ---------------- persistent recurrent kernel --------------------------------------
// 512 WGs launched; the first XCD to seat 64 WGs wins; its WGs (co-resident, shared
// L2) run the recurrence with sc0 L2-coherent handoffs. Everyone else exits.
// Publish = sc0 store (fast, same-XCD) + agent-scope mirror store (fallback).
__global__ __launch_bounds__(256, 2) void recurrent_kernel(
    const float* __restrict__ Hf,  const float* __restrict__ Whhf,
    const float* __restrict__ Hl,  const float* __restrict__ Whhl,
    const float* __restrict__ Mv,  const float* __restrict__ Ma,
    const float* __restrict__ V,   const float* __restrict__ aggr,
    const float* __restrict__ dfb, const float* __restrict__ dft,
    const float* __restrict__ dl,
    const float* __restrict__ bhhf,const float* __restrict__ bhhl,
    ull* __restrict__ h1tag,  ull* __restrict__ h2tag,
    ull* __restrict__ h1tagM, ull* __restrict__ h2tagM,
    unsigned* __restrict__ elec,
    float* __restrict__ h2all)
{
  // ---- election: first XCD to take 64 tickets wins; role = ticket ----
  __shared__ unsigned role_sh;
  if (threadIdx.x == 0){
    unsigned xcc;
    asm volatile("s_getreg_b32 %0, hwreg(HW_REG_XCC_ID)" : "=s"(xcc));
    xcc &= 7u;
    unsigned ticket = __hip_atomic_fetch_add(&elec[xcc], 1u,
                        __ATOMIC_RELAXED, __HIP_MEMORY_SCOPE_AGENT);
    if (ticket == 63u){
      unsigned exp0 = 0u;
      __hip_atomic_compare_exchange_strong(&elec[8], &exp0, xcc+1u,
          __ATOMIC_RELAXED, __ATOMIC_RELAXED, __HIP_MEMORY_SCOPE_AGENT);
    }
    unsigned w;
    do { w = __hip_atomic_load(&elec[8], __ATOMIC_RELAXED, __HIP_MEMORY_SCOPE_AGENT); }
    while (w == 0u);
    role_sh = ((w-1u) == xcc && ticket < 64u) ? ticket : 0xFFFFFFFFu;
  }
  __syncthreads();
  const unsigned role = role_sh;
  if (role == 0xFFFFFFFFu) return;

  const bool isF = (role < GWGS);
  const int wgi = isF ? (int)role : (int)role - GWGS;
  const int tid = threadIdx.x;
  const int g   = wgi*256 + tid;
  const int j   = g >> 4;        // output element 0..511
  const int sub = g & 15;        // col-slice within 16-lane team
  const int cv0 = sub*8;

  __shared__ float sh1[2][16*LSTR];
  __shared__ float sh2[2][16*LSTR];

  const int w0   = tid*2;                       // this thread's 2 poll words
  const int lofs = (w0>>5)*LSTR + (w0&31);      // LDS deposit offset

  const float* WI = isF ? Hf   : Hl;
  const float* WH = isF ? Whhf : Whhl;
  const float* WM = isF ? Mv   : Ma;
  const float* xv_src = isF ? V : aggr;

  float wI[3][32], wH[3][32], wM[3][8];
  #pragma unroll
  for (int r=0;r<3;r++){
    const int row = j + r*HID;
    const float4* qi = (const float4*)(WI + (size_t)row*HID + sub*32);
    const float4* qh = (const float4*)(WH + (size_t)row*HID + sub*32);
    #pragma unroll
    for (int i=0;i<8;i++){
      float4 a = qi[i]; wI[r][i*4+0]=a.x; wI[r][i*4+1]=a.y; wI[r][i*4+2]=a.z; wI[r][i*4+3]=a.w;
      float4 h = qh[i]; wH[r][i*4+0]=h.x; wH[r][i*4+1]=h.y; wH[r][i*4+2]=h.z; wH[r][i*4+3]=h.w;
    }
    const float4* qm = (const float4*)(WM + (size_t)row*F_DIM + cv0);
    #pragma unroll
    for (int i=0;i<2;i++){
      float4 m = qm[i]; wM[r][i*4+0]=m.x; wM[r][i*4+1]=m.y; wM[r][i*4+2]=m.z; wM[r][i*4+3]=m.w;
    }
  }
  float bI0[3]={0,0,0}, bIT[3]={0,0,0}, bH[3]={0,0,0};
  if (sub==0){
    #pragma unroll
    for (int r=0;r<3;r++){
      const int row = j + r*HID;
      float base = isF ? dfb[row] : dl[row];
      bI0[r] = base;
      bIT[r] = base + (isF ? dft[row] : 0.f);
      bH[r]  = isF ? bhhf[row] : bhhl[row];
    }
  }
  float hp = 0.f;

  for (int t=0; t<NSTEP; ++t){
    const int pw = t & 1, pr = pw ^ 1, par = t & 1;
    const unsigned tagc = (unsigned)t;      // tag of h produced at step t-1
    const unsigned tagp = (unsigned)(t+1);  // tag of h produced at step t

    // independent stream input (cached)
    float xv[8];
    {
      const float4* q = (const float4*)(xv_src + (size_t)t*F_DIM + cv0);
      float4 a = q[0], bb = q[1];
      xv[0]=a.x; xv[1]=a.y; xv[2]=a.z; xv[3]=a.w;
      xv[4]=bb.x; xv[5]=bb.y; xv[6]=bb.z; xv[7]=bb.w;
    }
    float aI0=0,aI1=0,aI2=0,aH0=0,aH1=0,aH2=0;
    #pragma unroll
    for (int k=0;k<8;k++){
      float vv=xv[k];
      aI0 += wM[0][k]*vv; aI1 += wM[1][k]*vv; aI2 += wM[2][k]*vv;
    }

    // ---- poll inputs (merged stale+fresh, one barrier) ----
    if (isF){
      if (t > 0){
        const ull* ps = h1tag + pr*HID + w0;   // stale h1[t-1]
        const ull* pf = h2tag + pr*HID + w0;   // fresh h2[t-1]  (critical)
        ull s0,s1,f0,f1;
        l2load4(ps, pf, s0,s1,f0,f1);
        pollpair(ps, h1tagM + pr*HID + w0, tagc, s0, s1);
        pollpair(pf, h2tagM + pr*HID + w0, tagc, f0, f1);
        *(float2*)&sh1[par][lofs] = make_float2(__uint_as_float((unsigned)s0), __uint_as_float((unsigned)s1));
        *(float2*)&sh2[par][lofs] = make_float2(__uint_as_float((unsigned)f0), __uint_as_float((unsigned)f1));
      }
    } else {
      const ull* pf = h1tag + pw*HID + w0;     // fresh h1[t]  (critical)
      ull s0=0,s1=0,f0=0,f1=0;
      if (t > 0){
        const ull* ps = h2tag + pr*HID + w0;   // stale h2[t-1]
        l2load4(ps, pf, s0,s1,f0,f1);
        pollpair(ps, h2tagM + pr*HID + w0, tagc, s0, s1);
        *(float2*)&sh2[par][lofs] = make_float2(__uint_as_float((unsigned)s0), __uint_as_float((unsigned)s1));
      } else {
        l2load2(pf, f0, f1);
      }
      pollpair(pf, h1tagM + pw*HID + w0, tagp, f0, f1);
      *(float2*)&sh1[par][lofs] = make_float2(__uint_as_float((unsigned)f0), __uint_as_float((unsigned)f1));
    }
    __syncthreads();

    // ---- dots from LDS ----
    if (isF){
      if (t > 0){
        const float4* q1 = (const float4*)&sh1[par][sub*LSTR];
        const float4* q2 = (const float4*)&sh2[par][sub*LSTR];
        #pragma unroll
        for (int i=0;i<8;i++){
          float4 x1 = q1[i], x2 = q2[i];
          aH0 += wH[0][i*4+0]*x1.x + wH[0][i*4+1]*x1.y + wH[0][i*4+2]*x1.z + wH[0][i*4+3]*x1.w;
          aH1 += wH[1][i*4+0]*x1.x + wH[1][i*4+1]*x1.y + wH[1][i*4+2]*x1.z + wH[1][i*4+3]*x1.w;
          aH2 += wH[2][i*4+0]*x1.x + wH[2][i*4+1]*x1.y + wH[2][i*4+2]*x1.z + wH[2][i*4+3]*x1.w;
          aI0 += wI[0][i*4+0]*x2.x + wI[0][i*4+1]*x2.y + wI[0][i*4+2]*x2.z + wI[0][i*4+3]*x2.w;
          aI1 += wI[1][i*4+0]*x2.x + wI[1][i*4+1]*x2.y + wI[1][i*4+2]*x2.z + wI[1][i*4+3]*x2.w;
          aI2 += wI[2][i*4+0]*x2.x + wI[2][i*4+1]*x2.y + wI[2][i*4+2]*x2.z + wI[2][i*4+3]*x2.w;
        }
      }
    } else {
      const float4* q1 = (const float4*)&sh1[par][sub*LSTR];
      if (t > 0){
        const float4* q2 = (const float4*)&sh2[par][sub*LSTR];
        #pragma unroll
        for (int i=0;i<8;i++){
          float4 x2 = q2[i];
          aH0 += wH[0][i*4+0]*x2.x + wH[0][i*4+1]*x2.y + wH[0][i*4+2]*x2.z + wH[0][i*4+3]*x2.w;
          aH1 += wH[1][i*4+0]*x2.x + wH[1][i*4+1]*x2.y + wH[1][i*4+2]*x2.z + wH[1][i*4+3]*x2.w;
          aH2 += wH[2][i*4+0]*x2.x + wH[2][i*4+1]*x2.y + wH[2][i*4+2]*x2.z + wH[2][i*4+3]*x2.w;
        }
      }
      #pragma unroll
      for (int i=0;i<8;i++){
        float4 x1 = q1[i];
        aI0 += wI[0][i*4+0]*x1.x + wI[0][i*4+1]*x1.y + wI[0][i*4+2]*x1.z + wI[0][i*4+3]*x1.w;
        aI1 += wI[1][i*4+0]*x1.x + wI[1][i*4+1]*x1.y + wI[1][i*4+2]*x1.z + wI[1][i*4+3]*x1.w;
        aI2 += wI[2][i*4+0]*x1.x + wI[2][i*4+1]*x1.y + wI[2][i*4+2]*x1.z + wI[2][i*4+3]*x1.w;
      }
    }
    aH0 = red16(aH0); aH1 = red16(aH1); aH2 = red16(aH2);
    aI0 = red16(aI0); aI1 = red16(aI1); aI2 = red16(aI2);

    if (sub==0){
      float gir = aI0 + (t>0 ? bIT[0] : bI0[0]);
      float giz = aI1 + (t>0 ? bIT[1] : bI0[1]);
      float gin = aI2 + (t>0 ? bIT[2] : bI0[2]);
      float r = sigmf(gir + aH0 + bH[0]);
      float z = sigmf(giz + aH1 + bH[1]);
      float n = tanhfast(gin + r*(aH2 + bH[2]));
      float hn = (1.f - z)*n + z*hp;
      hp = hn;
      ull pk = ((ull)tagp << 32) | (ull)__float_as_uint(hn);
      if (isF){
        l2store(&h1tag[pw*HID + j], pk);
        __hip_atomic_store(&h1tagM[pw*HID + j], pk, __ATOMIC_RELAXED, __HIP_MEMORY_SCOPE_AGENT);
      } else {
        l2store(&h2tag[pw*HID + j], pk);
        __hip_atomic_store(&h2tagM[pw*HID + j], pk, __ATOMIC_RELAXED, __HIP_MEMORY_SCOPE_AGENT);
        h2all[(size_t)t*HID + j] = hn;
      }
    }
  }
}

extern "C" void kernel_launch(void* const* d_in, const int* in_sizes, int n_in,
                              void* d_out, int out_size, void* d_ws, size_t ws_size,
                              hipStream_t stream) {
  const float* V      = (const float*)d_in[0];
  const float* E      = (const float*)d_in[1];
  const float* W_e    = (const float*)d_in[2];
  const float* W_fc1  = (const float*)d_in[3];
  const float* b_fc1  = (const float*)d_in[4];
  const float* w_ih_f = (const float*)d_in[5];
  const float* w_hh_f = (const float*)d_in[6];
  const float* b_ih_f = (const float*)d_in[7];
  const float* b_hh_f = (const float*)d_in[8];
  const float* W_v    = (const float*)d_in[9];
  /* W_h (d_in[10]) cancels in softmax — unused */
  const float* W_a    = (const float*)d_in[11];
  const float* W_fc2  = (const float*)d_in[12];
  const float* b_fc2  = (const float*)d_in[13];
  const float* w_ih_l = (const float*)d_in[14];
  const float* w_hh_l = (const float*)d_in[15];
  const float* b_ih_l = (const float*)d_in[16];
  const float* b_hh_l = (const float*)d_in[17];
  const float* W_fc3  = (const float*)d_in[18];
  const float* b_fc3  = (const float*)d_in[19];
  float* out = (float*)d_out;

  float* W = (float*)d_ws;
  size_t o = 0;
  float* Hf   = W + o; o += (size_t)1536*512;
  float* Hl   = W + o; o += (size_t)1536*512;
  float* Mv   = W + o; o += (size_t)1536*128;
  float* Ma   = W + o; o += (size_t)1536*128;
  float* M1   = W + o; o += (size_t)512*300;
  float* G1   = W + o; o += (size_t)512*512;
  float* u    = W + o; o += 128;
  float* t1   = W + o; o += 512;
  float* dfb  = W + o; o += 1536;
  float* dft  = W + o; o += 1536;
  float* dl   = W + o; o += 1536;
  float* aggr = W + o; o += (size_t)NSTEP*128;
  float* h2all= W + o; o += (size_t)NSTEP*512;
  o = (o + 1) & ~(size_t)1;  // 8B align
  ull* h1tag  = (ull*)(W + o); o += 2*2*HID;   // u64[2][512]
  ull* h2tag  = (ull*)(W + o); o += 2*2*HID;
  ull* h1tagM = (ull*)(W + o); o += 2*2*HID;   // agent-scope mirrors
  ull* h2tagM = (ull*)(W + o); o += 2*2*HID;
  unsigned* elec = (unsigned*)(W + o); o += 16; // [0..7]=per-XCD tickets, [8]=winner
  (void)ws_size; (void)in_sizes; (void)n_in; (void)out_size;

  // reset tags + mirrors + election each launch (captured => runs every replay)
  hipMemsetAsync(h1tag, 0, (4*2*HID)*sizeof(ull) + 16*sizeof(unsigned), stream);

  // u = W_v^T @ W_a[0]
  matvec<<<(128+3)/4, 256, 0, stream>>>(W_v, 128, 1, W_a, nullptr, u, 128, 128);
  // attention precompute (independent of recurrence)
  attn_kernel<<<NSTEP, 256, 0, stream>>>(V, E, u, aggr);
  // M1 = W_fc1[:,640:940] @ W_e                       [512x300]
  gemm_tiled<<<dim3(5,8), 256, 0, stream>>>(W_fc1+640, 940, W_e, 300, 0,
                                            nullptr, 0, nullptr, M1, 300, 512, 300, 300);
  // t1 = M1 @ b_fc3                                   [512]
  matvec<<<(512+3)/4, 256, 0, stream>>>(M1, 300, 0, b_fc3, nullptr, t1, 512, 300);
  // d_f_base = w_ih_f @ b_fc1 + b_ih_f                [1536]
  matvec<<<(1536+3)/4, 256, 0, stream>>>(w_ih_f, 512, 0, b_fc1, b_ih_f, dfb, 1536, 512);
  // d_f_tok = w_ih_f @ t1                             [1536]
  matvec<<<(1536+3)/4, 256, 0, stream>>>(w_ih_f, 512, 0, t1, nullptr, dft, 1536, 512);
  // d_l = w_ih_l @ b_fc2 + b_ih_l                     [1536]
  matvec<<<(1536+3)/4, 256, 0, stream>>>(w_ih_l, 512, 0, b_fc2, b_ih_l, dl, 1536, 512);
  // G1 = W_fc1[:,:512] + M1 @ W_fc3                   [512x512]
  gemm_tiled<<<dim3(8,8), 256, 0, stream>>>(M1, 300, W_fc3, 512, 0,
                                            W_fc1, 940, nullptr, G1, 512, 512, 512, 300);
  // Hf = w_ih_f @ G1                                  [1536x512]
  gemm_tiled<<<dim3(8,24), 256, 0, stream>>>(w_ih_f, 512, G1, 512, 0,
                                             nullptr, 0, nullptr, Hf, 512, 1536, 512, 512);
  // Hl = w_ih_l @ W_fc2[:,128:640]                    [1536x512]
  gemm_tiled<<<dim3(8,24), 256, 0, stream>>>(w_ih_l, 512, W_fc2+128, 640, 0,
                                             nullptr, 0, nullptr, Hl, 512, 1536, 512, 512);
  // Mv = w_ih_f @ W_fc1[:,512:640]                    [1536x128]
  gemm_tiled<<<dim3(2,24), 256, 0, stream>>>(w_ih_f, 512, W_fc1+512, 940, 0,
                                             nullptr, 0, nullptr, Mv, 128, 1536, 128, 512);
  // Ma = w_ih_l @ W_fc2[:,:128]                       [1536x128]
  gemm_tiled<<<dim3(2,24), 256, 0, stream>>>(w_ih_l, 512, W_fc2, 640, 0,
                                             nullptr, 0, nullptr, Ma, 128, 1536, 128, 512);
  // sequential recurrence: 512 WGs launched, 64 elected on one XCD
  recurrent_kernel<<<NWG, 256, 0, stream>>>(Hf, w_hh_f, Hl, w_hh_l, Mv, Ma,
                                            V, aggr, dfb, dft, dl, b_hh_f, b_hh_l,
                                            h1tag, h2tag, h1tagM, h2tagM, elec, h2all);
  // tokens = h2all @ W_fc3^T + b_fc3                  [4096x300]
  gemm_tiled<<<dim3(5,64), 256, 0, stream>>>(h2all, 512, W_fc3, 512, 1,
                                             nullptr, 0, b_fc3, out, 300, 4096, 300, 512);
}

// Round 6
// 21737.633 us; speedup vs baseline: 3.6555x; 3.6555x over previous
//
#include <hip/hip_runtime.h>
#include <math.h>

#define F_DIM 128
#define EMB 300
#define HID 512
#define NSTEP 4096
#define NNBR 64
#define NWG 64     // merged recurrent WGs (each does F-phase then L-phase)
#define NREP 4     // replication of published vectors (per-line poll pressure /4)
#define LSTR 36    // LDS row stride (floats)

typedef unsigned long long ull;

__device__ __forceinline__ float sigmf(float x){ return 1.0f/(1.0f + expf(-x)); }

__device__ __forceinline__ float red32(float v){
  v += __shfl_xor(v, 16);
  v += __shfl_xor(v, 8);
  v += __shfl_xor(v, 4);
  v += __shfl_xor(v, 2);
  v += __shfl_xor(v, 1);
  return v;
}

// wave0-only: poll 512 tagged u64 (8 contiguous words per lane = one 64B line)
// until every tag matches, then deposit values into LDS buf[R][C]=h[32R+C].
// Pure compiler atomics: no inline asm, no register-tear hazard.
__device__ __forceinline__ void gather512(const ull* __restrict__ base, int lane,
                                          unsigned tag, float* __restrict__ buf){
  const ull* p = base + lane*8;
  ull v[8];
  for(;;){
    #pragma unroll
    for (int k=0;k<8;k++)
      v[k] = __hip_atomic_load(p+k, __ATOMIC_RELAXED, __HIP_MEMORY_SCOPE_AGENT);
    unsigned bad = 0u;
    #pragma unroll
    for (int k=0;k<8;k++) bad |= ((unsigned)(v[k]>>32)) ^ tag;
    if (__all(bad == 0u)) break;
  }
  float* d = &buf[(lane>>2)*LSTR + 8*(lane&3)];   // e=8*lane+k -> R=e>>5, C=e&31
  #pragma unroll
  for (int k=0;k<8;k++) d[k] = __uint_as_float((unsigned)(v[k] & 0xffffffffu));
}

// 3-gate dot of 16 LDS floats against row-slices
__device__ __forceinline__ void dot16(const float* __restrict__ buf, int sub,
                                      const float w0[16], const float w1[16], const float w2[16],
                                      float& d0, float& d1, float& d2){
  const float4* q = (const float4*)&buf[(sub>>1)*LSTR + (sub&1)*16];
  #pragma unroll
  for (int i=0;i<4;i++){
    float4 x = q[i];
    d0 += w0[i*4+0]*x.x + w0[i*4+1]*x.y + w0[i*4+2]*x.z + w0[i*4+3]*x.w;
    d1 += w1[i*4+0]*x.x + w1[i*4+1]*x.y + w1[i*4+2]*x.z + w1[i*4+3]*x.w;
    d2 += w2[i*4+0]*x.x + w2[i*4+1]*x.y + w2[i*4+2]*x.z + w2[i*4+3]*x.w;
  }
}

// ---------------- generic tiled f32 GEMM: C[M,N] = A[M,K]@B[K,N] (+D) (+bias_n) ----
__global__ void gemm_tiled(const float* __restrict__ A, int lda,
                           const float* __restrict__ B, int ldb, int transB,
                           const float* __restrict__ D, int ldd,
                           const float* __restrict__ bias,
                           float* __restrict__ C, int ldc,
                           int M, int N, int K)
{
  __shared__ float As[16][65];
  __shared__ float Bs[16][65];
  const int tid = threadIdx.x;
  const int m0 = blockIdx.y*64, n0 = blockIdx.x*64;
  const int ty = tid>>4, tx = tid&15;
  float acc[4][4] = {};
  for (int k0=0; k0<K; k0+=16){
    #pragma unroll
    for (int i=0;i<4;i++){
      int idx = tid + i*256;
      int m = idx>>4, k = idx&15;
      float va = 0.f;
      if (m0+m < M && k0+k < K) va = A[(size_t)(m0+m)*lda + k0+k];
      As[k][m] = va;
      int k2 = idx>>6, n = idx&63;
      float vb = 0.f;
      if (k0+k2 < K && n0+n < N)
        vb = transB ? B[(size_t)(n0+n)*ldb + k0+k2] : B[(size_t)(k0+k2)*ldb + n0+n];
      Bs[k2][n] = vb;
    }
    __syncthreads();
    #pragma unroll
    for (int k=0;k<16;k++){
      float a[4], b[4];
      #pragma unroll
      for (int i=0;i<4;i++) a[i] = As[k][ty*4+i];
      #pragma unroll
      for (int j=0;j<4;j++) b[j] = Bs[k][tx*4+j];
      #pragma unroll
      for (int i=0;i<4;i++)
        #pragma unroll
        for (int j=0;j<4;j++) acc[i][j] += a[i]*b[j];
    }
    __syncthreads();
  }
  #pragma unroll
  for (int i=0;i<4;i++){
    int m = m0 + ty*4 + i;
    if (m >= M) continue;
    #pragma unroll
    for (int j=0;j<4;j++){
      int n = n0 + tx*4 + j;
      if (n >= N) continue;
      float v = acc[i][j];
      if (D)    v += D[(size_t)m*ldd + n];
      if (bias) v += bias[n];
      C[(size_t)m*ldc + n] = v;
    }
  }
}

// ---------------- matvec: out[m] = sum_k A[m,k]*x[k] (+bias[m]); transA reads A[k,m]
__global__ void matvec(const float* __restrict__ A, int lda, int transA,
                       const float* __restrict__ x, const float* __restrict__ bias,
                       float* __restrict__ out, int M, int K)
{
  const int wave = threadIdx.x>>6, lane = threadIdx.x&63;
  const int row = blockIdx.x*4 + wave;
  if (row >= M) return;
  float s = 0.f;
  for (int k=lane; k<K; k+=64)
    s += (transA ? A[(size_t)k*lda + row] : A[(size_t)row*lda + k]) * x[k];
  s += __shfl_xor(s,32); s += __shfl_xor(s,16); s += __shfl_xor(s,8);
  s += __shfl_xor(s,4);  s += __shfl_xor(s,2);  s += __shfl_xor(s,1);
  if (lane==0) out[row] = s + (bias ? bias[row] : 0.f);
}

// ---------------- attention precompute: aggr[t] = softmax((v_t+e_t)@u) @ (v_t+e_t)
__global__ void attn_kernel(const float* __restrict__ V, const float* __restrict__ E,
                            const float* __restrict__ u, float* __restrict__ aggr)
{
  __shared__ float Es[NNBR][F_DIM+1];
  __shared__ float us[F_DIM];
  __shared__ float attn[NNBR];
  const int t = blockIdx.x, tid = threadIdx.x;
  if (tid < F_DIM) us[tid] = u[tid];
  const float* e = E + (size_t)t*NNBR*F_DIM;
  const float* v = V + (size_t)t*F_DIM;
  for (int idx=tid; idx<NNBR*F_DIM; idx+=256){
    int k = idx>>7, f = idx&127;
    Es[k][f] = e[idx] + v[f];
  }
  __syncthreads();
  if (tid < NNBR){
    float s = 0.f;
    #pragma unroll
    for (int f=0; f<F_DIM; f++) s += Es[tid][f]*us[f];
    float m = s;
    m = fmaxf(m, __shfl_xor(m,32)); m = fmaxf(m, __shfl_xor(m,16));
    m = fmaxf(m, __shfl_xor(m,8));  m = fmaxf(m, __shfl_xor(m,4));
    m = fmaxf(m, __shfl_xor(m,2));  m = fmaxf(m, __shfl_xor(m,1));
    float p = expf(s - m);
    float sum = p;
    sum += __shfl_xor(sum,32); sum += __shfl_xor(sum,16); sum += __shfl_xor(sum,8);
    sum += __shfl_xor(sum,4);  sum += __shfl_xor(sum,2);  sum += __shfl_xor(sum,1);
    attn[tid] = p / sum;
  }
  __syncthreads();
  if (tid < F_DIM){
    float a = 0.f;
    #pragma unroll
    for (int k=0; k<NNBR; k++) a += attn[k]*Es[k][tid];
    aggr[(size_t)t*F_DIM + tid] = a;
  }
}

// ---------------- merged persistent recurrent kernel -------------------------------
// 64 WGs, 1/CU. Each WG computes an 8-row slice of h1[t] (phase A) then h2[t]
// (phase B). Per phase exactly ONE fresh gather: wave 0 polls its WG's replica of
// the x4-replicated tagged vector (relaxed agent atomics) into LDS while the other
// waves compute the off-critical Whh dot; one barrier per phase.
__global__ __launch_bounds__(256, 1) void recurrent_kernel(
    const float* __restrict__ Hf,  const float* __restrict__ Whhf,
    const float* __restrict__ Hl,  const float* __restrict__ Whhl,
    const float* __restrict__ Mv,  const float* __restrict__ Ma,
    const float* __restrict__ V,   const float* __restrict__ aggr,
    const float* __restrict__ dfb, const float* __restrict__ dft,
    const float* __restrict__ dl,
    const float* __restrict__ bhhf,const float* __restrict__ bhhl,
    ull* __restrict__ h1rep, ull* __restrict__ h2rep,
    float* __restrict__ h2all)
{
  const int tid = threadIdx.x, wgi = blockIdx.x;
  const int g   = wgi*256 + tid;
  const int j   = g >> 5;          // output element 0..511
  const int sub = g & 31;          // 32-way col slice
  const int c0  = sub*16, cv0 = sub*4;
  const int lane = tid & 63;
  const bool pollw = (tid < 64);
  const int rep = wgi & (NREP-1);

  __shared__ float b1[2][16*LSTR];  // h1 staged per parity
  __shared__ float b2[2][16*LSTR];  // h2 staged per parity

  // weights in registers: 4 matrices x 3 rows x 16 cols (+ 2 x 3 x 4)
  float wIf[3][16], wHf[3][16], wIl[3][16], wHl[3][16], wMf[3][4], wMl[3][4];
  #pragma unroll
  for (int r=0;r<3;r++){
    const size_t row = (size_t)(j + r*HID);
    const float4* a1p = (const float4*)(Hf   + row*HID + c0);
    const float4* a2p = (const float4*)(Whhf + row*HID + c0);
    const float4* a3p = (const float4*)(Hl   + row*HID + c0);
    const float4* a4p = (const float4*)(Whhl + row*HID + c0);
    #pragma unroll
    for (int i=0;i<4;i++){
      float4 v1=a1p[i], v2=a2p[i], v3=a3p[i], v4=a4p[i];
      wIf[r][i*4+0]=v1.x; wIf[r][i*4+1]=v1.y; wIf[r][i*4+2]=v1.z; wIf[r][i*4+3]=v1.w;
      wHf[r][i*4+0]=v2.x; wHf[r][i*4+1]=v2.y; wHf[r][i*4+2]=v2.z; wHf[r][i*4+3]=v2.w;
      wIl[r][i*4+0]=v3.x; wIl[r][i*4+1]=v3.y; wIl[r][i*4+2]=v3.z; wIl[r][i*4+3]=v3.w;
      wHl[r][i*4+0]=v4.x; wHl[r][i*4+1]=v4.y; wHl[r][i*4+2]=v4.z; wHl[r][i*4+3]=v4.w;
    }
    float4 m1 = *(const float4*)(Mv + row*F_DIM + cv0);
    float4 m2 = *(const float4*)(Ma + row*F_DIM + cv0);
    wMf[r][0]=m1.x; wMf[r][1]=m1.y; wMf[r][2]=m1.z; wMf[r][3]=m1.w;
    wMl[r][0]=m2.x; wMl[r][1]=m2.y; wMl[r][2]=m2.z; wMl[r][3]=m2.w;
  }
  float bA0[3]={0,0,0}, bAT[3]={0,0,0}, bAH[3]={0,0,0}, bB[3]={0,0,0}, bBH[3]={0,0,0};
  if (sub==0){
    #pragma unroll
    for (int r=0;r<3;r++){
      const int row = j + r*HID;
      bA0[r] = dfb[row];
      bAT[r] = dfb[row] + dft[row];
      bAH[r] = bhhf[row];
      bB[r]  = dl[row];
      bBH[r] = bhhl[row];
    }
  }
  float hp1 = 0.f, hp2 = 0.f;

  for (int t=0; t<NSTEP; ++t){
    const int par = t & 1, prv = par ^ 1;
    const unsigned tagc = (unsigned)t;      // tag of h2[t-1]
    const unsigned tagp = (unsigned)(t+1);  // tag of h1[t], h2[t]

    // ================= phase A: h1[t] = GRU_f(h1[t-1], h2[t-1], v[t]) ==============
    float aI0,aI1,aI2, aH0=0,aH1=0,aH2=0;
    {
      float4 xv = *(const float4*)(V + (size_t)t*F_DIM + cv0);
      aI0 = wMf[0][0]*xv.x + wMf[0][1]*xv.y + wMf[0][2]*xv.z + wMf[0][3]*xv.w;
      aI1 = wMf[1][0]*xv.x + wMf[1][1]*xv.y + wMf[1][2]*xv.z + wMf[1][3]*xv.w;
      aI2 = wMf[2][0]*xv.x + wMf[2][1]*xv.y + wMf[2][2]*xv.z + wMf[2][3]*xv.w;
    }
    if (t > 0){
      dot16(&b1[prv][0], sub, wHf[0], wHf[1], wHf[2], aH0, aH1, aH2);
      if (pollw)
        gather512(h2rep + ((size_t)prv*NREP + rep)*HID, lane, tagc, &b2[par][0]);
    }
    aH0 = red32(aH0); aH1 = red32(aH1); aH2 = red32(aH2);
    __syncthreads();
    if (t > 0)
      dot16(&b2[par][0], sub, wIf[0], wIf[1], wIf[2], aI0, aI1, aI2);
    aI0 = red32(aI0); aI1 = red32(aI1); aI2 = red32(aI2);

    if (sub==0){
      float gir = aI0 + (t>0 ? bAT[0] : bA0[0]);
      float giz = aI1 + (t>0 ? bAT[1] : bA0[1]);
      float gin = aI2 + (t>0 ? bAT[2] : bA0[2]);
      float r = sigmf(gir + aH0 + bAH[0]);
      float z = sigmf(giz + aH1 + bAH[1]);
      float n = tanhf(gin + r*(aH2 + bAH[2]));
      float hn = (1.f - z)*n + z*hp1;
      hp1 = hn;
      ull pk = ((ull)tagp << 32) | (ull)__float_as_uint(hn);
      #pragma unroll
      for (int r2=0;r2<NREP;r2++)
        __hip_atomic_store(&h1rep[((size_t)par*NREP + r2)*HID + j], pk,
                           __ATOMIC_RELAXED, __HIP_MEMORY_SCOPE_AGENT);
    }

    // ================= phase B: h2[t] = GRU_l(h2[t-1], h1[t], aggr[t]) =============
    float cI0,cI1,cI2, cH0=0,cH1=0,cH2=0;
    {
      float4 xa = *(const float4*)(aggr + (size_t)t*F_DIM + cv0);
      cI0 = wMl[0][0]*xa.x + wMl[0][1]*xa.y + wMl[0][2]*xa.z + wMl[0][3]*xa.w;
      cI1 = wMl[1][0]*xa.x + wMl[1][1]*xa.y + wMl[1][2]*xa.z + wMl[1][3]*xa.w;
      cI2 = wMl[2][0]*xa.x + wMl[2][1]*xa.y + wMl[2][2]*xa.z + wMl[2][3]*xa.w;
    }
    if (t > 0)
      dot16(&b2[par][0], sub, wHl[0], wHl[1], wHl[2], cH0, cH1, cH2);
    if (pollw)
      gather512(h1rep + ((size_t)par*NREP + rep)*HID, lane, tagp, &b1[par][0]);
    cH0 = red32(cH0); cH1 = red32(cH1); cH2 = red32(cH2);
    __syncthreads();
    dot16(&b1[par][0], sub, wIl[0], wIl[1], wIl[2], cI0, cI1, cI2);
    cI0 = red32(cI0); cI1 = red32(cI1); cI2 = red32(cI2);

    if (sub==0){
      float r = sigmf(cI0 + bB[0] + cH0 + bBH[0]);
      float z = sigmf(cI1 + bB[1] + cH1 + bBH[1]);
      float n = tanhf(cI2 + bB[2] + r*(cH2 + bBH[2]));
      float hn = (1.f - z)*n + z*hp2;
      hp2 = hn;
      ull pk = ((ull)tagp << 32) | (ull)__float_as_uint(hn);
      #pragma unroll
      for (int r2=0;r2<NREP;r2++)
        __hip_atomic_store(&h2rep[((size_t)par*NREP + r2)*HID + j], pk,
                           __ATOMIC_RELAXED, __HIP_MEMORY_SCOPE_AGENT);
      h2all[(size_t)t*HID + j] = hn;
    }
  }
}

extern "C" void kernel_launch(void* const* d_in, const int* in_sizes, int n_in,
                              void* d_out, int out_size, void* d_ws, size_t ws_size,
                              hipStream_t stream) {
  const float* V      = (const float*)d_in[0];
  const float* E      = (const float*)d_in[1];
  const float* W_e    = (const float*)d_in[2];
  const float* W_fc1  = (const float*)d_in[3];
  const float* b_fc1  = (const float*)d_in[4];
  const float* w_ih_f = (const float*)d_in[5];
  const float* w_hh_f = (const float*)d_in[6];
  const float* b_ih_f = (const float*)d_in[7];
  const float* b_hh_f = (const float*)d_in[8];
  const float* W_v    = (const float*)d_in[9];
  /* W_h (d_in[10]) cancels in softmax — unused */
  const float* W_a    = (const float*)d_in[11];
  const float* W_fc2  = (const float*)d_in[12];
  const float* b_fc2  = (const float*)d_in[13];
  const float* w_ih_l = (const float*)d_in[14];
  const float* w_hh_l = (const float*)d_in[15];
  const float* b_ih_l = (const float*)d_in[16];
  const float* b_hh_l = (const float*)d_in[17];
  const float* W_fc3  = (const float*)d_in[18];
  const float* b_fc3  = (const float*)d_in[19];
  float* out = (float*)d_out;

  float* W = (float*)d_ws;
  size_t o = 0;
  float* Hf   = W + o; o += (size_t)1536*512;
  float* Hl   = W + o; o += (size_t)1536*512;
  float* Mv   = W + o; o += (size_t)1536*128;
  float* Ma   = W + o; o += (size_t)1536*128;
  float* M1   = W + o; o += (size_t)512*300;
  float* G1   = W + o; o += (size_t)512*512;
  float* u    = W + o; o += 128;
  float* t1   = W + o; o += 512;
  float* dfb  = W + o; o += 1536;
  float* dft  = W + o; o += 1536;
  float* dl   = W + o; o += 1536;
  float* aggr = W + o; o += (size_t)NSTEP*128;
  float* h2all= W + o; o += (size_t)NSTEP*512;
  o = (o + 3) & ~(size_t)3;  // 16B align
  ull* h1rep = (ull*)(W + o); o += 2*(2*NREP*HID);   // u64[2][NREP][512]
  ull* h2rep = (ull*)(W + o); o += 2*(2*NREP*HID);
  (void)ws_size; (void)in_sizes; (void)n_in; (void)out_size;

  // reset tag buffers each launch (captured => every replay; kills ABA)
  hipMemsetAsync(h1rep, 0, 2ull*(2*NREP*HID)*sizeof(ull), stream);

  // u = W_v^T @ W_a[0]
  matvec<<<(128+3)/4, 256, 0, stream>>>(W_v, 128, 1, W_a, nullptr, u, 128, 128);
  // attention precompute (independent of recurrence)
  attn_kernel<<<NSTEP, 256, 0, stream>>>(V, E, u, aggr);
  // M1 = W_fc1[:,640:940] @ W_e                       [512x300]
  gemm_tiled<<<dim3(5,8), 256, 0, stream>>>(W_fc1+640, 940, W_e, 300, 0,
                                            nullptr, 0, nullptr, M1, 300, 512, 300, 300);
  // t1 = M1 @ b_fc3                                   [512]
  matvec<<<(512+3)/4, 256, 0, stream>>>(M1, 300, 0, b_fc3, nullptr, t1, 512, 300);
  // d_f_base = w_ih_f @ b_fc1 + b_ih_f                [1536]
  matvec<<<(1536+3)/4, 256, 0, stream>>>(w_ih_f, 512, 0, b_fc1, b_ih_f, dfb, 1536, 512);
  // d_f_tok = w_ih_f @ t1                             [1536]
  matvec<<<(1536+3)/4, 256, 0, stream>>>(w_ih_f, 512, 0, t1, nullptr, dft, 1536, 512);
  // d_l = w_ih_l @ b_fc2 + b_ih_l                     [1536]
  matvec<<<(1536+3)/4, 256, 0, stream>>>(w_ih_l, 512, 0, b_fc2, b_ih_l, dl, 1536, 512);
  // G1 = W_fc1[:,:512] + M1 @ W_fc3                   [512x512]
  gemm_tiled<<<dim3(8,8), 256, 0, stream>>>(M1, 300, W_fc3, 512, 0,
                                            W_fc1, 940, nullptr, G1, 512, 512, 512, 300);
  // Hf = w_ih_f @ G1                                  [1536x512]
  gemm_tiled<<<dim3(8,24), 256, 0, stream>>>(w_ih_f, 512, G1, 512, 0,
                                             nullptr, 0, nullptr, Hf, 512, 1536, 512, 512);
  // Hl = w_ih_l @ W_fc2[:,128:640]                    [1536x512]
  gemm_tiled<<<dim3(8,24), 256, 0, stream>>>(w_ih_l, 512, W_fc2+128, 640, 0,
                                             nullptr, 0, nullptr, Hl, 512, 1536, 512, 512);
  // Mv = w_ih_f @ W_fc1[:,512:640]                    [1536x128]
  gemm_tiled<<<dim3(2,24), 256, 0, stream>>>(w_ih_f, 512, W_fc1+512, 940, 0,
                                             nullptr, 0, nullptr, Mv, 128, 1536, 128, 512);
  // Ma = w_ih_l @ W_fc2[:,:128]                       [1536x128]
  gemm_tiled<<<dim3(2,24), 256, 0, stream>>>(w_ih_l, 512, W_fc2, 640, 0,
                                             nullptr, 0, nullptr, Ma, 128, 1536, 128, 512);
  // merged sequential recurrence: 64 WGs, 1/CU
  recurrent_kernel<<<NWG, 256, 0, stream>>>(Hf, w_hh_f, Hl, w_hh_l, Mv, Ma,
                                            V, aggr, dfb, dft, dl, b_hh_f, b_hh_l,
                                            h1rep, h2rep, h2all);
  // tokens = h2all @ W_fc3^T + b_fc3                  [4096x300]
  gemm_tiled<<<dim3(5,64), 256, 0, stream>>>(h2all, 512, W_fc3, 512, 1,
                                             nullptr, 0, b_fc3, out, 300, 4096, 300, 512);
}

// Round 7
// 15633.255 us; speedup vs baseline: 5.0829x; 1.3905x over previous
//
#include <hip/hip_runtime.h>
#include <math.h>

#define F_DIM 128
#define EMB 300
#define HID 512
#define NSTEP 4096
#define NNBR 64
#define GWGS 32   // workgroups per recurrent group (F and L)
#define NREP 4    // replication of published vectors (pollers per line: 32 -> 8)
#define LSTR 36   // LDS row stride (floats) — 16-lane teams => broadcast reads, 0 conflicts

typedef unsigned long long ull;

__device__ __forceinline__ float sigmf(float x){ return 1.0f/(1.0f + expf(-x)); }

__device__ __forceinline__ float red16(float v){
  v += __shfl_xor(v, 8);
  v += __shfl_xor(v, 4);
  v += __shfl_xor(v, 2);
  v += __shfl_xor(v, 1);
  return v;
}

// poll 2 consecutive packed {tag<<32|val} words until both tags match; deposit to LDS.
// Per-thread individual exit -> poll pressure decays as data arrives.
__device__ __forceinline__ void poll2(const ull* __restrict__ p, unsigned tag,
                                      float* __restrict__ lds){
  ull a, b;
  for(;;){
    a = __hip_atomic_load(p,   __ATOMIC_RELAXED, __HIP_MEMORY_SCOPE_AGENT);
    b = __hip_atomic_load(p+1, __ATOMIC_RELAXED, __HIP_MEMORY_SCOPE_AGENT);
    if (((((unsigned)(a>>32)) ^ tag) | (((unsigned)(b>>32)) ^ tag)) == 0u) break;
  }
  *(float2*)lds = make_float2(__uint_as_float((unsigned)a), __uint_as_float((unsigned)b));
}

// ---------------- generic tiled f32 GEMM: C[M,N] = A[M,K]@B[K,N] (+D) (+bias_n) ----
__global__ void gemm_tiled(const float* __restrict__ A, int lda,
                           const float* __restrict__ B, int ldb, int transB,
                           const float* __restrict__ D, int ldd,
                           const float* __restrict__ bias,
                           float* __restrict__ C, int ldc,
                           int M, int N, int K)
{
  __shared__ float As[16][65];
  __shared__ float Bs[16][65];
  const int tid = threadIdx.x;
  const int m0 = blockIdx.y*64, n0 = blockIdx.x*64;
  const int ty = tid>>4, tx = tid&15;
  float acc[4][4] = {};
  for (int k0=0; k0<K; k0+=16){
    #pragma unroll
    for (int i=0;i<4;i++){
      int idx = tid + i*256;
      int m = idx>>4, k = idx&15;
      float va = 0.f;
      if (m0+m < M && k0+k < K) va = A[(size_t)(m0+m)*lda + k0+k];
      As[k][m] = va;
      int k2 = idx>>6, n = idx&63;
      float vb = 0.f;
      if (k0+k2 < K && n0+n < N)
        vb = transB ? B[(size_t)(n0+n)*ldb + k0+k2] : B[(size_t)(k0+k2)*ldb + n0+n];
      Bs[k2][n] = vb;
    }
    __syncthreads();
    #pragma unroll
    for (int k=0;k<16;k++){
      float a[4], b[4];
      #pragma unroll
      for (int i=0;i<4;i++) a[i] = As[k][ty*4+i];
      #pragma unroll
      for (int j=0;j<4;j++) b[j] = Bs[k][tx*4+j];
      #pragma unroll
      for (int i=0;i<4;i++)
        #pragma unroll
        for (int j=0;j<4;j++) acc[i][j] += a[i]*b[j];
    }
    __syncthreads();
  }
  #pragma unroll
  for (int i=0;i<4;i++){
    int m = m0 + ty*4 + i;
    if (m >= M) continue;
    #pragma unroll
    for (int j=0;j<4;j++){
      int n = n0 + tx*4 + j;
      if (n >= N) continue;
      float v = acc[i][j];
      if (D)    v += D[(size_t)m*ldd + n];
      if (bias) v += bias[n];
      C[(size_t)m*ldc + n] = v;
    }
  }
}

// ---------------- matvec: out[m] = sum_k A[m,k]*x[k] (+bias[m]); transA reads A[k,m]
__global__ void matvec(const float* __restrict__ A, int lda, int transA,
                       const float* __restrict__ x, const float* __restrict__ bias,
                       float* __restrict__ out, int M, int K)
{
  const int wave = threadIdx.x>>6, lane = threadIdx.x&63;
  const int row = blockIdx.x*4 + wave;
  if (row >= M) return;
  float s = 0.f;
  for (int k=lane; k<K; k+=64)
    s += (transA ? A[(size_t)k*lda + row] : A[(size_t)row*lda + k]) * x[k];
  s += __shfl_xor(s,32); s += __shfl_xor(s,16); s += __shfl_xor(s,8);
  s += __shfl_xor(s,4);  s += __shfl_xor(s,2);  s += __shfl_xor(s,1);
  if (lane==0) out[row] = s + (bias ? bias[row] : 0.f);
}

// ---------------- attention precompute: aggr[t] = softmax((v_t+e_t)@u) @ (v_t+e_t)
__global__ void attn_kernel(const float* __restrict__ V, const float* __restrict__ E,
                            const float* __restrict__ u, float* __restrict__ aggr)
{
  __shared__ float Es[NNBR][F_DIM+1];
  __shared__ float us[F_DIM];
  __shared__ float attn[NNBR];
  const int t = blockIdx.x, tid = threadIdx.x;
  if (tid < F_DIM) us[tid] = u[tid];
  const float* e = E + (size_t)t*NNBR*F_DIM;
  const float* v = V + (size_t)t*F_DIM;
  for (int idx=tid; idx<NNBR*F_DIM; idx+=256){
    int k = idx>>7, f = idx&127;
    Es[k][f] = e[idx] + v[f];
  }
  __syncthreads();
  if (tid < NNBR){
    float s = 0.f;
    #pragma unroll
    for (int f=0; f<F_DIM; f++) s += Es[tid][f]*us[f];
    float m = s;
    m = fmaxf(m, __shfl_xor(m,32)); m = fmaxf(m, __shfl_xor(m,16));
    m = fmaxf(m, __shfl_xor(m,8));  m = fmaxf(m, __shfl_xor(m,4));
    m = fmaxf(m, __shfl_xor(m,2));  m = fmaxf(m, __shfl_xor(m,1));
    float p = expf(s - m);
    float sum = p;
    sum += __shfl_xor(sum,32); sum += __shfl_xor(sum,16); sum += __shfl_xor(sum,8);
    sum += __shfl_xor(sum,4);  sum += __shfl_xor(sum,2);  sum += __shfl_xor(sum,1);
    attn[tid] = p / sum;
  }
  __syncthreads();
  if (tid < F_DIM){
    float a = 0.f;
    #pragma unroll
    for (int k=0; k<NNBR; k++) a += attn[k]*Es[k][tid];
    aggr[(size_t)t*F_DIM + tid] = a;
  }
}

// ---------------- persistent recurrent kernel: 64 wgs (32 F + 32 L) ----------------
// R3-proven skeleton: per-thread 2-word tagged polls (individual exit), 16-lane
// teams (broadcast LDS reads, 0 bank conflicts), stale-dot overlapped with the other
// group's publish. New: x4-replicated publish written in parallel by lanes sub<4;
// each WG polls replica wgi&3 (8 polling WGs per line instead of 32).
__global__ __launch_bounds__(256, 1) void recurrent_kernel(
    const float* __restrict__ Hf,  const float* __restrict__ Whhf,
    const float* __restrict__ Hl,  const float* __restrict__ Whhl,
    const float* __restrict__ Mv,  const float* __restrict__ Ma,
    const float* __restrict__ V,   const float* __restrict__ aggr,
    const float* __restrict__ dfb, const float* __restrict__ dft,
    const float* __restrict__ dl,
    const float* __restrict__ bhhf,const float* __restrict__ bhhl,
    ull* __restrict__ h1rep, ull* __restrict__ h2rep,
    float* __restrict__ h2all)
{
  const int b = blockIdx.x;
  const bool isF = (b < GWGS);
  const int wgi = isF ? b : b - GWGS;
  const int tid = threadIdx.x;
  const int g   = wgi*256 + tid;
  const int j   = g >> 4;        // output element 0..511
  const int sub = g & 15;        // col-slice within 16-lane team
  const int cv0 = sub*8;
  const int rep = wgi & (NREP-1);

  __shared__ float sh1[2][16*LSTR];   // h1 vector staged per parity
  __shared__ float sh2[2][16*LSTR];   // h2 vector staged per parity

  const int w0   = tid*2;                   // this thread's 2 poll words
  const int lofs = (w0>>5)*LSTR + (w0&31);  // LDS deposit offset

  const float* WI = isF ? Hf   : Hl;
  const float* WH = isF ? Whhf : Whhl;
  const float* WM = isF ? Mv   : Ma;
  const float* xv_src = isF ? V : aggr;
  ull* __restrict__ own   = isF ? h1rep : h2rep;  // what this group publishes
  ull* __restrict__ fresh = isF ? h2rep : h1rep;  // critical input
  ull* __restrict__ stale = isF ? h1rep : h2rep;  // off-critical input

  float wI[3][32], wH[3][32], wM[3][8];
  #pragma unroll
  for (int r=0;r<3;r++){
    const int row = j + r*HID;
    const float4* qi = (const float4*)(WI + (size_t)row*HID + sub*32);
    const float4* qh = (const float4*)(WH + (size_t)row*HID + sub*32);
    #pragma unroll
    for (int i=0;i<8;i++){
      float4 a = qi[i]; wI[r][i*4+0]=a.x; wI[r][i*4+1]=a.y; wI[r][i*4+2]=a.z; wI[r][i*4+3]=a.w;
      float4 h = qh[i]; wH[r][i*4+0]=h.x; wH[r][i*4+1]=h.y; wH[r][i*4+2]=h.z; wH[r][i*4+3]=h.w;
    }
    const float4* qm = (const float4*)(WM + (size_t)row*F_DIM + cv0);
    #pragma unroll
    for (int i=0;i<2;i++){
      float4 m = qm[i]; wM[r][i*4+0]=m.x; wM[r][i*4+1]=m.y; wM[r][i*4+2]=m.z; wM[r][i*4+3]=m.w;
    }
  }
  // biases in ALL lanes (each lane computes gates redundantly; enables parallel publish)
  float bI0[3], bIT[3], bH[3];
  #pragma unroll
  for (int r=0;r<3;r++){
    const int row = j + r*HID;
    float base = isF ? dfb[row] : dl[row];
    bI0[r] = base;
    bIT[r] = base + (isF ? dft[row] : 0.f);
    bH[r]  = isF ? bhhf[row] : bhhl[row];
  }
  float hp = 0.f;

  for (int t=0; t<NSTEP; ++t){
    const int pw = t & 1, pr = pw ^ 1, par = t & 1;
    const unsigned tagc = (unsigned)t;      // tag of h produced at step t-1
    const unsigned tagp = (unsigned)(t+1);  // tag of h produced at step t

    // independent stream input (cached)
    float xv[8];
    {
      const float4* q = (const float4*)(xv_src + (size_t)t*F_DIM + cv0);
      float4 a = q[0], bb = q[1];
      xv[0]=a.x; xv[1]=a.y; xv[2]=a.z; xv[3]=a.w;
      xv[4]=bb.x; xv[5]=bb.y; xv[6]=bb.z; xv[7]=bb.w;
    }
    float aI0=0,aI1=0,aI2=0,aH0=0,aH1=0,aH2=0;
    #pragma unroll
    for (int k=0;k<8;k++){
      float vv=xv[k];
      aI0 += wM[0][k]*vv; aI1 += wM[1][k]*vv; aI2 += wM[2][k]*vv;
    }

    // ---- phase A: stale own-state (published one phase ago — near-instant) ----
    float* shS = isF ? &sh1[par][0] : &sh2[par][0];
    if (t > 0){
      poll2(stale + ((size_t)pr*NREP + rep)*HID + w0, tagc, &shS[lofs]);
    }
    __syncthreads();
    if (t > 0){
      const float4* q = (const float4*)&shS[sub*LSTR];
      #pragma unroll
      for (int i=0;i<8;i++){
        float4 x = q[i];
        aH0 += wH[0][i*4+0]*x.x + wH[0][i*4+1]*x.y + wH[0][i*4+2]*x.z + wH[0][i*4+3]*x.w;
        aH1 += wH[1][i*4+0]*x.x + wH[1][i*4+1]*x.y + wH[1][i*4+2]*x.z + wH[1][i*4+3]*x.w;
        aH2 += wH[2][i*4+0]*x.x + wH[2][i*4+1]*x.y + wH[2][i*4+2]*x.z + wH[2][i*4+3]*x.w;
      }
    }
    aH0 = red16(aH0); aH1 = red16(aH1); aH2 = red16(aH2);

    // ---- phase B: fresh other-state (the critical input) ----
    float* shF = isF ? &sh2[par][0] : &sh1[par][0];
    const int fpar = isF ? pr : pw;             // F reads h2[t-1]; L reads h1[t]
    const unsigned ftag = isF ? tagc : tagp;
    if (isF ? (t > 0) : true){
      poll2(fresh + ((size_t)fpar*NREP + rep)*HID + w0, ftag, &shF[lofs]);
    }
    __syncthreads();
    if (isF ? (t > 0) : true){
      const float4* q = (const float4*)&shF[sub*LSTR];
      #pragma unroll
      for (int i=0;i<8;i++){
        float4 x = q[i];
        aI0 += wI[0][i*4+0]*x.x + wI[0][i*4+1]*x.y + wI[0][i*4+2]*x.z + wI[0][i*4+3]*x.w;
        aI1 += wI[1][i*4+0]*x.x + wI[1][i*4+1]*x.y + wI[1][i*4+2]*x.z + wI[1][i*4+3]*x.w;
        aI2 += wI[2][i*4+0]*x.x + wI[2][i*4+1]*x.y + wI[2][i*4+2]*x.z + wI[2][i*4+3]*x.w;
      }
    }
    aI0 = red16(aI0); aI1 = red16(aI1); aI2 = red16(aI2);

    // gates in ALL lanes (red16 is an all-reduce) -> parallel replica publish
    {
      float gir = aI0 + (t>0 ? bIT[0] : bI0[0]);
      float giz = aI1 + (t>0 ? bIT[1] : bI0[1]);
      float gin = aI2 + (t>0 ? bIT[2] : bI0[2]);
      float r = sigmf(gir + aH0 + bH[0]);
      float z = sigmf(giz + aH1 + bH[1]);
      float n = tanhf(gin + r*(aH2 + bH[2]));
      float hn = (1.f - z)*n + z*hp;
      hp = hn;
      ull pk = ((ull)tagp << 32) | (ull)__float_as_uint(hn);
      if (sub < NREP)
        __hip_atomic_store(&own[((size_t)pw*NREP + sub)*HID + j], pk,
                           __ATOMIC_RELAXED, __HIP_MEMORY_SCOPE_AGENT);
      if (!isF && sub == 0)
        h2all[(size_t)t*HID + j] = hn;
    }
  }
}

extern "C" void kernel_launch(void* const* d_in, const int* in_sizes, int n_in,
                              void* d_out, int out_size, void* d_ws, size_t ws_size,
                              hipStream_t stream) {
  const float* V      = (const float*)d_in[0];
  const float* E      = (const float*)d_in[1];
  const float* W_e    = (const float*)d_in[2];
  const float* W_fc1  = (const float*)d_in[3];
  const float* b_fc1  = (const float*)d_in[4];
  const float* w_ih_f = (const float*)d_in[5];
  const float* w_hh_f = (const float*)d_in[6];
  const float* b_ih_f = (const float*)d_in[7];
  const float* b_hh_f = (const float*)d_in[8];
  const float* W_v    = (const float*)d_in[9];
  /* W_h (d_in[10]) cancels in softmax — unused */
  const float* W_a    = (const float*)d_in[11];
  const float* W_fc2  = (const float*)d_in[12];
  const float* b_fc2  = (const float*)d_in[13];
  const float* w_ih_l = (const float*)d_in[14];
  const float* w_hh_l = (const float*)d_in[15];
  const float* b_ih_l = (const float*)d_in[16];
  const float* b_hh_l = (const float*)d_in[17];
  const float* W_fc3  = (const float*)d_in[18];
  const float* b_fc3  = (const float*)d_in[19];
  float* out = (float*)d_out;

  float* W = (float*)d_ws;
  size_t o = 0;
  float* Hf   = W + o; o += (size_t)1536*512;
  float* Hl   = W + o; o += (size_t)1536*512;
  float* Mv   = W + o; o += (size_t)1536*128;
  float* Ma   = W + o; o += (size_t)1536*128;
  float* M1   = W + o; o += (size_t)512*300;
  float* G1   = W + o; o += (size_t)512*512;
  float* u    = W + o; o += 128;
  float* t1   = W + o; o += 512;
  float* dfb  = W + o; o += 1536;
  float* dft  = W + o; o += 1536;
  float* dl   = W + o; o += 1536;
  float* aggr = W + o; o += (size_t)NSTEP*128;
  float* h2all= W + o; o += (size_t)NSTEP*512;
  o = (o + 3) & ~(size_t)3;  // 16B align
  ull* h1rep = (ull*)(W + o); o += 2*(2*NREP*HID);   // u64[2][NREP][512]
  ull* h2rep = (ull*)(W + o); o += 2*(2*NREP*HID);
  (void)ws_size; (void)in_sizes; (void)n_in; (void)out_size;

  // reset tag buffers each launch (captured => every replay; kills ABA)
  hipMemsetAsync(h1rep, 0, 2ull*(2*NREP*HID)*sizeof(ull), stream);

  // u = W_v^T @ W_a[0]
  matvec<<<(128+3)/4, 256, 0, stream>>>(W_v, 128, 1, W_a, nullptr, u, 128, 128);
  // attention precompute (independent of recurrence)
  attn_kernel<<<NSTEP, 256, 0, stream>>>(V, E, u, aggr);
  // M1 = W_fc1[:,640:940] @ W_e                       [512x300]
  gemm_tiled<<<dim3(5,8), 256, 0, stream>>>(W_fc1+640, 940, W_e, 300, 0,
                                            nullptr, 0, nullptr, M1, 300, 512, 300, 300);
  // t1 = M1 @ b_fc3                                   [512]
  matvec<<<(512+3)/4, 256, 0, stream>>>(M1, 300, 0, b_fc3, nullptr, t1, 512, 300);
  // d_f_base = w_ih_f @ b_fc1 + b_ih_f                [1536]
  matvec<<<(1536+3)/4, 256, 0, stream>>>(w_ih_f, 512, 0, b_fc1, b_ih_f, dfb, 1536, 512);
  // d_f_tok = w_ih_f @ t1                             [1536]
  matvec<<<(1536+3)/4, 256, 0, stream>>>(w_ih_f, 512, 0, t1, nullptr, dft, 1536, 512);
  // d_l = w_ih_l @ b_fc2 + b_ih_l                     [1536]
  matvec<<<(1536+3)/4, 256, 0, stream>>>(w_ih_l, 512, 0, b_fc2, b_ih_l, dl, 1536, 512);
  // G1 = W_fc1[:,:512] + M1 @ W_fc3                   [512x512]
  gemm_tiled<<<dim3(8,8), 256, 0, stream>>>(M1, 300, W_fc3, 512, 0,
                                            W_fc1, 940, nullptr, G1, 512, 512, 512, 300);
  // Hf = w_ih_f @ G1                                  [1536x512]
  gemm_tiled<<<dim3(8,24), 256, 0, stream>>>(w_ih_f, 512, G1, 512, 0,
                                             nullptr, 0, nullptr, Hf, 512, 1536, 512, 512);
  // Hl = w_ih_l @ W_fc2[:,128:640]                    [1536x512]
  gemm_tiled<<<dim3(8,24), 256, 0, stream>>>(w_ih_l, 512, W_fc2+128, 640, 0,
                                             nullptr, 0, nullptr, Hl, 512, 1536, 512, 512);
  // Mv = w_ih_f @ W_fc1[:,512:640]                    [1536x128]
  gemm_tiled<<<dim3(2,24), 256, 0, stream>>>(w_ih_f, 512, W_fc1+512, 940, 0,
                                             nullptr, 0, nullptr, Mv, 128, 1536, 128, 512);
  // Ma = w_ih_l @ W_fc2[:,:128]                       [1536x128]
  gemm_tiled<<<dim3(2,24), 256, 0, stream>>>(w_ih_l, 512, W_fc2, 640, 0,
                                             nullptr, 0, nullptr, Ma, 128, 1536, 128, 512);
  // sequential recurrence: 64 persistent wgs (32 F + 32 L)
  recurrent_kernel<<<2*GWGS, 256, 0, stream>>>(Hf, w_hh_f, Hl, w_hh_l, Mv, Ma,
                                               V, aggr, dfb, dft, dl, b_hh_f, b_hh_l,
                                               h1rep, h2rep, h2all);
  // tokens = h2all @ W_fc3^T + b_fc3                  [4096x300]
  gemm_tiled<<<dim3(5,64), 256, 0, stream>>>(h2all, 512, W_fc3, 512, 1,
                                             nullptr, 0, b_fc3, out, 300, 4096, 300, 512);
}

// Round 8
// 15227.542 us; speedup vs baseline: 5.2184x; 1.0266x over previous
//
#include <hip/hip_runtime.h>
#include <math.h>

#define F_DIM 128
#define EMB 300
#define HID 512
#define NSTEP 4096
#define NNBR 64
#define GWGS 32   // workgroups per recurrent group (F and L)
#define NREP 4    // replication of published vectors (pollers per line: 32 -> 8)
#define LSTR 36   // LDS row stride (floats) — 16-lane teams => broadcast reads, 0 conflicts

typedef unsigned long long ull;

__device__ __forceinline__ float sigmf(float x){ return 1.0f/(1.0f + expf(-x)); }

__device__ __forceinline__ float red16(float v){
  v += __shfl_xor(v, 8);
  v += __shfl_xor(v, 4);
  v += __shfl_xor(v, 2);
  v += __shfl_xor(v, 1);
  return v;
}

__device__ __forceinline__ bool badtag(ull a, ull b, unsigned tag){
  return ((((unsigned)(a>>32)) ^ tag) | (((unsigned)(b>>32)) ^ tag)) != 0u;
}

// poll 2 consecutive packed {tag<<32|val} words until both tags match; deposit to LDS.
__device__ __forceinline__ void poll2(const ull* __restrict__ p, unsigned tag,
                                      float* __restrict__ lds){
  ull a, b;
  for(;;){
    a = __hip_atomic_load(p,   __ATOMIC_RELAXED, __HIP_MEMORY_SCOPE_AGENT);
    b = __hip_atomic_load(p+1, __ATOMIC_RELAXED, __HIP_MEMORY_SCOPE_AGENT);
    if (!badtag(a, b, tag)) break;
  }
  *(float2*)lds = make_float2(__uint_as_float((unsigned)a), __uint_as_float((unsigned)b));
}

// ---------------- generic tiled f32 GEMM: C[M,N] = A[M,K]@B[K,N] (+D) (+bias_n) ----
__global__ void gemm_tiled(const float* __restrict__ A, int lda,
                           const float* __restrict__ B, int ldb, int transB,
                           const float* __restrict__ D, int ldd,
                           const float* __restrict__ bias,
                           float* __restrict__ C, int ldc,
                           int M, int N, int K)
{
  __shared__ float As[16][65];
  __shared__ float Bs[16][65];
  const int tid = threadIdx.x;
  const int m0 = blockIdx.y*64, n0 = blockIdx.x*64;
  const int ty = tid>>4, tx = tid&15;
  float acc[4][4] = {};
  for (int k0=0; k0<K; k0+=16){
    #pragma unroll
    for (int i=0;i<4;i++){
      int idx = tid + i*256;
      int m = idx>>4, k = idx&15;
      float va = 0.f;
      if (m0+m < M && k0+k < K) va = A[(size_t)(m0+m)*lda + k0+k];
      As[k][m] = va;
      int k2 = idx>>6, n = idx&63;
      float vb = 0.f;
      if (k0+k2 < K && n0+n < N)
        vb = transB ? B[(size_t)(n0+n)*ldb + k0+k2] : B[(size_t)(k0+k2)*ldb + n0+n];
      Bs[k2][n] = vb;
    }
    __syncthreads();
    #pragma unroll
    for (int k=0;k<16;k++){
      float a[4], b[4];
      #pragma unroll
      for (int i=0;i<4;i++) a[i] = As[k][ty*4+i];
      #pragma unroll
      for (int j=0;j<4;j++) b[j] = Bs[k][tx*4+j];
      #pragma unroll
      for (int i=0;i<4;i++)
        #pragma unroll
        for (int j=0;j<4;j++) acc[i][j] += a[i]*b[j];
    }
    __syncthreads();
  }
  #pragma unroll
  for (int i=0;i<4;i++){
    int m = m0 + ty*4 + i;
    if (m >= M) continue;
    #pragma unroll
    for (int j=0;j<4;j++){
      int n = n0 + tx*4 + j;
      if (n >= N) continue;
      float v = acc[i][j];
      if (D)    v += D[(size_t)m*ldd + n];
      if (bias) v += bias[n];
      C[(size_t)m*ldc + n] = v;
    }
  }
}

// ---------------- matvec: out[m] = sum_k A[m,k]*x[k] (+bias[m]); transA reads A[k,m]
__global__ void matvec(const float* __restrict__ A, int lda, int transA,
                       const float* __restrict__ x, const float* __restrict__ bias,
                       float* __restrict__ out, int M, int K)
{
  const int wave = threadIdx.x>>6, lane = threadIdx.x&63;
  const int row = blockIdx.x*4 + wave;
  if (row >= M) return;
  float s = 0.f;
  for (int k=lane; k<K; k+=64)
    s += (transA ? A[(size_t)k*lda + row] : A[(size_t)row*lda + k]) * x[k];
  s += __shfl_xor(s,32); s += __shfl_xor(s,16); s += __shfl_xor(s,8);
  s += __shfl_xor(s,4);  s += __shfl_xor(s,2);  s += __shfl_xor(s,1);
  if (lane==0) out[row] = s + (bias ? bias[row] : 0.f);
}

// ---------------- attention precompute: aggr[t] = softmax((v_t+e_t)@u) @ (v_t+e_t)
__global__ void attn_kernel(const float* __restrict__ V, const float* __restrict__ E,
                            const float* __restrict__ u, float* __restrict__ aggr)
{
  __shared__ float Es[NNBR][F_DIM+1];
  __shared__ float us[F_DIM];
  __shared__ float attn[NNBR];
  const int t = blockIdx.x, tid = threadIdx.x;
  if (tid < F_DIM) us[tid] = u[tid];
  const float* e = E + (size_t)t*NNBR*F_DIM;
  const float* v = V + (size_t)t*F_DIM;
  for (int idx=tid; idx<NNBR*F_DIM; idx+=256){
    int k = idx>>7, f = idx&127;
    Es[k][f] = e[idx] + v[f];
  }
  __syncthreads();
  if (tid < NNBR){
    float s = 0.f;
    #pragma unroll
    for (int f=0; f<F_DIM; f++) s += Es[tid][f]*us[f];
    float m = s;
    m = fmaxf(m, __shfl_xor(m,32)); m = fmaxf(m, __shfl_xor(m,16));
    m = fmaxf(m, __shfl_xor(m,8));  m = fmaxf(m, __shfl_xor(m,4));
    m = fmaxf(m, __shfl_xor(m,2));  m = fmaxf(m, __shfl_xor(m,1));
    float p = expf(s - m);
    float sum = p;
    sum += __shfl_xor(sum,32); sum += __shfl_xor(sum,16); sum += __shfl_xor(sum,8);
    sum += __shfl_xor(sum,4);  sum += __shfl_xor(sum,2);  sum += __shfl_xor(sum,1);
    attn[tid] = p / sum;
  }
  __syncthreads();
  if (tid < F_DIM){
    float a = 0.f;
    #pragma unroll
    for (int k=0; k<NNBR; k++) a += attn[k]*Es[k][tid];
    aggr[(size_t)t*F_DIM + tid] = a;
  }
}

// ---------------- persistent recurrent kernel: 64 wgs (32 F + 32 L) ----------------
// R7 skeleton (per-thread 2-word tagged polls, 16-lane teams, x4 replicated publish)
// + critical-path reorder: the FRESH sweep is issued FIRST (loads in flight), the
// stale poll + stale dot + red16 run underneath it, then the fresh check loop.
__global__ __launch_bounds__(256, 1) void recurrent_kernel(
    const float* __restrict__ Hf,  const float* __restrict__ Whhf,
    const float* __restrict__ Hl,  const float* __restrict__ Whhl,
    const float* __restrict__ Mv,  const float* __restrict__ Ma,
    const float* __restrict__ V,   const float* __restrict__ aggr,
    const float* __restrict__ dfb, const float* __restrict__ dft,
    const float* __restrict__ dl,
    const float* __restrict__ bhhf,const float* __restrict__ bhhl,
    ull* __restrict__ h1rep, ull* __restrict__ h2rep,
    float* __restrict__ h2all)
{
  const int b = blockIdx.x;
  const bool isF = (b < GWGS);
  const int wgi = isF ? b : b - GWGS;
  const int tid = threadIdx.x;
  const int g   = wgi*256 + tid;
  const int j   = g >> 4;        // output element 0..511
  const int sub = g & 15;        // col-slice within 16-lane team
  const int cv0 = sub*8;
  const int rep = wgi & (NREP-1);

  __shared__ float sh1[2][16*LSTR];   // h1 vector staged per parity
  __shared__ float sh2[2][16*LSTR];   // h2 vector staged per parity

  const int w0   = tid*2;                   // this thread's 2 poll words
  const int lofs = (w0>>5)*LSTR + (w0&31);  // LDS deposit offset

  const float* WI = isF ? Hf   : Hl;
  const float* WH = isF ? Whhf : Whhl;
  const float* WM = isF ? Mv   : Ma;
  const float* xv_src = isF ? V : aggr;
  ull* __restrict__ own   = isF ? h1rep : h2rep;  // what this group publishes
  ull* __restrict__ fresh = isF ? h2rep : h1rep;  // critical input
  ull* __restrict__ stale = isF ? h1rep : h2rep;  // off-critical input

  float wI[3][32], wH[3][32], wM[3][8];
  #pragma unroll
  for (int r=0;r<3;r++){
    const int row = j + r*HID;
    const float4* qi = (const float4*)(WI + (size_t)row*HID + sub*32);
    const float4* qh = (const float4*)(WH + (size_t)row*HID + sub*32);
    #pragma unroll
    for (int i=0;i<8;i++){
      float4 a = qi[i]; wI[r][i*4+0]=a.x; wI[r][i*4+1]=a.y; wI[r][i*4+2]=a.z; wI[r][i*4+3]=a.w;
      float4 h = qh[i]; wH[r][i*4+0]=h.x; wH[r][i*4+1]=h.y; wH[r][i*4+2]=h.z; wH[r][i*4+3]=h.w;
    }
    const float4* qm = (const float4*)(WM + (size_t)row*F_DIM + cv0);
    #pragma unroll
    for (int i=0;i<2;i++){
      float4 m = qm[i]; wM[r][i*4+0]=m.x; wM[r][i*4+1]=m.y; wM[r][i*4+2]=m.z; wM[r][i*4+3]=m.w;
    }
  }
  // biases in ALL lanes (gates computed redundantly -> parallel replica publish)
  float bI0[3], bIT[3], bH[3];
  #pragma unroll
  for (int r=0;r<3;r++){
    const int row = j + r*HID;
    float base = isF ? dfb[row] : dl[row];
    bI0[r] = base;
    bIT[r] = base + (isF ? dft[row] : 0.f);
    bH[r]  = isF ? bhhf[row] : bhhl[row];
  }
  float hp = 0.f;

  for (int t=0; t<NSTEP; ++t){
    const int pw = t & 1, pr = pw ^ 1, par = t & 1;
    const unsigned tagc = (unsigned)t;      // tag of h produced at step t-1
    const unsigned tagp = (unsigned)(t+1);  // tag of h produced at step t
    const int fpar = isF ? pr : pw;         // F reads h2[t-1]; L reads h1[t]
    const unsigned ftag = isF ? tagc : tagp;
    const bool hasF = isF ? (t > 0) : true;
    const bool hasS = (t > 0);
    const ull* fp = fresh + ((size_t)fpar*NREP + rep)*HID + w0;

    // ---- issue first FRESH sweep immediately (loads in flight under stale work) ----
    ull f0 = 0, f1 = 0;
    if (hasF){
      f0 = __hip_atomic_load(fp,   __ATOMIC_RELAXED, __HIP_MEMORY_SCOPE_AGENT);
      f1 = __hip_atomic_load(fp+1, __ATOMIC_RELAXED, __HIP_MEMORY_SCOPE_AGENT);
    }

    // independent stream input (cached)
    float xv[8];
    {
      const float4* q = (const float4*)(xv_src + (size_t)t*F_DIM + cv0);
      float4 a = q[0], bb = q[1];
      xv[0]=a.x; xv[1]=a.y; xv[2]=a.z; xv[3]=a.w;
      xv[4]=bb.x; xv[5]=bb.y; xv[6]=bb.z; xv[7]=bb.w;
    }
    float aI0=0,aI1=0,aI2=0,aH0=0,aH1=0,aH2=0;
    #pragma unroll
    for (int k=0;k<8;k++){
      float vv=xv[k];
      aI0 += wM[0][k]*vv; aI1 += wM[1][k]*vv; aI2 += wM[2][k]*vv;
    }

    // ---- stale own-group state (published one step ago — near-instant) ----
    float* shS = isF ? &sh1[par][0] : &sh2[par][0];
    if (hasS)
      poll2(stale + ((size_t)pr*NREP + rep)*HID + w0, tagc, &shS[lofs]);
    __syncthreads();
    if (hasS){
      const float4* q = (const float4*)&shS[sub*LSTR];
      #pragma unroll
      for (int i=0;i<8;i++){
        float4 x = q[i];
        aH0 += wH[0][i*4+0]*x.x + wH[0][i*4+1]*x.y + wH[0][i*4+2]*x.z + wH[0][i*4+3]*x.w;
        aH1 += wH[1][i*4+0]*x.x + wH[1][i*4+1]*x.y + wH[1][i*4+2]*x.z + wH[1][i*4+3]*x.w;
        aH2 += wH[2][i*4+0]*x.x + wH[2][i*4+1]*x.y + wH[2][i*4+2]*x.z + wH[2][i*4+3]*x.w;
      }
    }
    aH0 = red16(aH0); aH1 = red16(aH1); aH2 = red16(aH2);

    // ---- fresh other-group state (critical): check the early sweep, then poll ----
    float* shF = isF ? &sh2[par][0] : &sh1[par][0];
    if (hasF){
      while (badtag(f0, f1, ftag)){
        f0 = __hip_atomic_load(fp,   __ATOMIC_RELAXED, __HIP_MEMORY_SCOPE_AGENT);
        f1 = __hip_atomic_load(fp+1, __ATOMIC_RELAXED, __HIP_MEMORY_SCOPE_AGENT);
      }
      *(float2*)&shF[lofs] = make_float2(__uint_as_float((unsigned)f0),
                                         __uint_as_float((unsigned)f1));
    }
    __syncthreads();
    if (hasF){
      const float4* q = (const float4*)&shF[sub*LSTR];
      #pragma unroll
      for (int i=0;i<8;i++){
        float4 x = q[i];
        aI0 += wI[0][i*4+0]*x.x + wI[0][i*4+1]*x.y + wI[0][i*4+2]*x.z + wI[0][i*4+3]*x.w;
        aI1 += wI[1][i*4+0]*x.x + wI[1][i*4+1]*x.y + wI[1][i*4+2]*x.z + wI[1][i*4+3]*x.w;
        aI2 += wI[2][i*4+0]*x.x + wI[2][i*4+1]*x.y + wI[2][i*4+2]*x.z + wI[2][i*4+3]*x.w;
      }
    }
    aI0 = red16(aI0); aI1 = red16(aI1); aI2 = red16(aI2);

    // gates in ALL lanes (red16 is an all-reduce) -> parallel replica publish
    {
      float gir = aI0 + (t>0 ? bIT[0] : bI0[0]);
      float giz = aI1 + (t>0 ? bIT[1] : bI0[1]);
      float gin = aI2 + (t>0 ? bIT[2] : bI0[2]);
      float r = sigmf(gir + aH0 + bH[0]);
      float z = sigmf(giz + aH1 + bH[1]);
      float n = tanhf(gin + r*(aH2 + bH[2]));
      float hn = (1.f - z)*n + z*hp;
      hp = hn;
      ull pk = ((ull)tagp << 32) | (ull)__float_as_uint(hn);
      if (sub < NREP)
        __hip_atomic_store(&own[((size_t)pw*NREP + sub)*HID + j], pk,
                           __ATOMIC_RELAXED, __HIP_MEMORY_SCOPE_AGENT);
      if (!isF && sub == 0)
        h2all[(size_t)t*HID + j] = hn;
    }
  }
}

extern "C" void kernel_launch(void* const* d_in, const int* in_sizes, int n_in,
                              void* d_out, int out_size, void* d_ws, size_t ws_size,
                              hipStream_t stream) {
  const float* V      = (const float*)d_in[0];
  const float* E      = (const float*)d_in[1];
  const float* W_e    = (const float*)d_in[2];
  const float* W_fc1  = (const float*)d_in[3];
  const float* b_fc1  = (const float*)d_in[4];
  const float* w_ih_f = (const float*)d_in[5];
  const float* w_hh_f = (const float*)d_in[6];
  const float* b_ih_f = (const float*)d_in[7];
  const float* b_hh_f = (const float*)d_in[8];
  const float* W_v    = (const float*)d_in[9];
  /* W_h (d_in[10]) cancels in softmax — unused */
  const float* W_a    = (const float*)d_in[11];
  const float* W_fc2  = (const float*)d_in[12];
  const float* b_fc2  = (const float*)d_in[13];
  const float* w_ih_l = (const float*)d_in[14];
  const float* w_hh_l = (const float*)d_in[15];
  const float* b_ih_l = (const float*)d_in[16];
  const float* b_hh_l = (const float*)d_in[17];
  const float* W_fc3  = (const float*)d_in[18];
  const float* b_fc3  = (const float*)d_in[19];
  float* out = (float*)d_out;

  float* W = (float*)d_ws;
  size_t o = 0;
  float* Hf   = W + o; o += (size_t)1536*512;
  float* Hl   = W + o; o += (size_t)1536*512;
  float* Mv   = W + o; o += (size_t)1536*128;
  float* Ma   = W + o; o += (size_t)1536*128;
  float* M1   = W + o; o += (size_t)512*300;
  float* G1   = W + o; o += (size_t)512*512;
  float* u    = W + o; o += 128;
  float* t1   = W + o; o += 512;
  float* dfb  = W + o; o += 1536;
  float* dft  = W + o; o += 1536;
  float* dl   = W + o; o += 1536;
  float* aggr = W + o; o += (size_t)NSTEP*128;
  float* h2all= W + o; o += (size_t)NSTEP*512;
  o = (o + 3) & ~(size_t)3;  // 16B align
  ull* h1rep = (ull*)(W + o); o += 2*(2*NREP*HID);   // u64[2][NREP][512]
  ull* h2rep = (ull*)(W + o); o += 2*(2*NREP*HID);
  (void)ws_size; (void)in_sizes; (void)n_in; (void)out_size;

  // reset tag buffers each launch (captured => every replay; kills ABA)
  hipMemsetAsync(h1rep, 0, 2ull*(2*NREP*HID)*sizeof(ull), stream);

  // u = W_v^T @ W_a[0]
  matvec<<<(128+3)/4, 256, 0, stream>>>(W_v, 128, 1, W_a, nullptr, u, 128, 128);
  // attention precompute (independent of recurrence)
  attn_kernel<<<NSTEP, 256, 0, stream>>>(V, E, u, aggr);
  // M1 = W_fc1[:,640:940] @ W_e                       [512x300]
  gemm_tiled<<<dim3(5,8), 256, 0, stream>>>(W_fc1+640, 940, W_e, 300, 0,
                                            nullptr, 0, nullptr, M1, 300, 512, 300, 300);
  // t1 = M1 @ b_fc3                                   [512]
  matvec<<<(512+3)/4, 256, 0, stream>>>(M1, 300, 0, b_fc3, nullptr, t1, 512, 300);
  // d_f_base = w_ih_f @ b_fc1 + b_ih_f                [1536]
  matvec<<<(1536+3)/4, 256, 0, stream>>>(w_ih_f, 512, 0, b_fc1, b_ih_f, dfb, 1536, 512);
  // d_f_tok = w_ih_f @ t1                             [1536]
  matvec<<<(1536+3)/4, 256, 0, stream>>>(w_ih_f, 512, 0, t1, nullptr, dft, 1536, 512);
  // d_l = w_ih_l @ b_fc2 + b_ih_l                     [1536]
  matvec<<<(1536+3)/4, 256, 0, stream>>>(w_ih_l, 512, 0, b_fc2, b_ih_l, dl, 1536, 512);
  // G1 = W_fc1[:,:512] + M1 @ W_fc3                   [512x512]
  gemm_tiled<<<dim3(8,8), 256, 0, stream>>>(M1, 300, W_fc3, 512, 0,
                                            W_fc1, 940, nullptr, G1, 512, 512, 512, 300);
  // Hf = w_ih_f @ G1                                  [1536x512]
  gemm_tiled<<<dim3(8,24), 256, 0, stream>>>(w_ih_f, 512, G1, 512, 0,
                                             nullptr, 0, nullptr, Hf, 512, 1536, 512, 512);
  // Hl = w_ih_l @ W_fc2[:,128:640]                    [1536x512]
  gemm_tiled<<<dim3(8,24), 256, 0, stream>>>(w_ih_l, 512, W_fc2+128, 640, 0,
                                             nullptr, 0, nullptr, Hl, 512, 1536, 512, 512);
  // Mv = w_ih_f @ W_fc1[:,512:640]                    [1536x128]
  gemm_tiled<<<dim3(2,24), 256, 0, stream>>>(w_ih_f, 512, W_fc1+512, 940, 0,
                                             nullptr, 0, nullptr, Mv, 128, 1536, 128, 512);
  // Ma = w_ih_l @ W_fc2[:,:128]                       [1536x128]
  gemm_tiled<<<dim3(2,24), 256, 0, stream>>>(w_ih_l, 512, W_fc2, 640, 0,
                                             nullptr, 0, nullptr, Ma, 128, 1536, 128, 512);
  // sequential recurrence: 64 persistent wgs (32 F + 32 L)
  recurrent_kernel<<<2*GWGS, 256, 0, stream>>>(Hf, w_hh_f, Hl, w_hh_l, Mv, Ma,
                                               V, aggr, dfb, dft, dl, b_hh_f, b_hh_l,
                                               h1rep, h2rep, h2all);
  // tokens = h2all @ W_fc3^T + b_fc3                  [4096x300]
  gemm_tiled<<<dim3(5,64), 256, 0, stream>>>(h2all, 512, W_fc3, 512, 1,
                                             nullptr, 0, b_fc3, out, 300, 4096, 300, 512);
}